// Round 4
// baseline (1594.509 us; speedup 1.0000x reference)
//
#include <hip/hip_runtime.h>
#include <cstdint>
#include <cstddef>

#define N_NODES 100000
#define N_EDGES 3200000
#define F_IN    256
#define HID     16
#define KH      32      // K stacks (2) * HID (16)
#define C_OUT   16

#define W_LOG   7
#define W       128                     // dst-window (nodes per bucket)
#define NBKT    782                     // ceil(N_NODES / W)
#define CAP     4608                    // bucket capacity (mean 4092, +8 sigma)
#define EPB     4096                    // edges per partition block

typedef short  bf16x8 __attribute__((ext_vector_type(8)));
typedef float  f32x4  __attribute__((ext_vector_type(4)));
typedef unsigned short u16x8 __attribute__((ext_vector_type(8)));

__device__ __forceinline__ unsigned short f2bf(float f) {
    uint32_t u = __builtin_bit_cast(uint32_t, f);
    u += 0x7fffu + ((u >> 16) & 1u);      // round-to-nearest-even
    return (unsigned short)(u >> 16);
}
__device__ __forceinline__ float bf2f(unsigned short s) {
    return __builtin_bit_cast(float, (uint32_t)s << 16);
}

// ---------------- edge partition into dst-window buckets ----------------
// packed = (src << 7) | (dst & 127); bucket = dst >> 7.
// Per block: LDS histogram -> one global chunk-claim atomic per touched bucket
// -> scatter to bucket frontier (L2-resident, lines fully filled).
__global__ __launch_bounds__(256) void k_part(const int* __restrict__ src,
                                              const int* __restrict__ dst,
                                              int* __restrict__ gcur,
                                              unsigned int* __restrict__ bucketed) {
    __shared__ int hist[NBKT];
    __shared__ int lcur[NBKT];
    __shared__ unsigned int pbuf[EPB];
    __shared__ unsigned short bbuf[EPB];
    int tid = threadIdx.x;
    for (int i = tid; i < NBKT; i += 256) hist[i] = 0;
    __syncthreads();
    int e0 = blockIdx.x * EPB;
    int cnt = min(EPB, N_EDGES - e0);
    for (int i = tid; i < cnt; i += 256) {
        int s = src[e0 + i], d = dst[e0 + i];
        int b = d >> W_LOG;
        pbuf[i] = ((unsigned int)s << W_LOG) | (unsigned int)(d & (W - 1));
        bbuf[i] = (unsigned short)b;
        atomicAdd(&hist[b], 1);
    }
    __syncthreads();
    for (int b = tid; b < NBKT; b += 256) {
        int h = hist[b];
        lcur[b] = h > 0 ? atomicAdd(&gcur[b], h) : 0;   // global base within bucket
    }
    __syncthreads();
    for (int i = tid; i < cnt; i += 256) {
        int b = bbuf[i];
        int pos = atomicAdd(&lcur[b], 1);
        if (pos < CAP) bucketed[(size_t)b * CAP + pos] = pbuf[i];
    }
}

// ---------------- per-bucket degree histogram -> dinv ----------------
__global__ __launch_bounds__(256) void k_bdeg(const unsigned int* __restrict__ bucketed,
                                              const int* __restrict__ gcur,
                                              float* __restrict__ dinv) {
    __shared__ int dh[W];
    int tid = threadIdx.x, b = blockIdx.x;
    if (tid < W) dh[tid] = 0;
    __syncthreads();
    int cnt = min(gcur[b], CAP);
    const unsigned int* bp = bucketed + (size_t)b * CAP;
    for (int i = tid; i < cnt; i += 256) atomicAdd(&dh[bp[i] & (W - 1)], 1);
    __syncthreads();
    int node = b * W + tid;
    if (tid < W && node < N_NODES) {
        int d = dh[tid];
        dinv[node] = d > 0 ? rsqrtf((float)d) : 0.f;
    }
}

// ---------------- layer-1 GEMM via bf16 MFMA (unchanged from round 3) ----------------
__global__ __launch_bounds__(256) void k_gemm1(
    const float* __restrict__ x, const float* __restrict__ wi,
    const float* __restrict__ wr, unsigned short* __restrict__ h1b,
    float* __restrict__ r1) {
    __shared__ unsigned short wt[64 * 256];     // 32KB  W^T: [col][k] bf16, slot-swizzled
    __shared__ unsigned short abuf[2][64 * 32]; // 8KB   A: [row][k] bf16, slot-swizzled

    int tid = threadIdx.x;

    for (int i = tid; i < 8192; i += 256) {
        int ksk = i >> 12, f = (i >> 4) & 255, o = i & 15;
        int col = ksk * 16 + o;
        int slot = (f >> 3) ^ (col & 7);
        wt[col * 256 + slot * 8 + (f & 7)] = f2bf(wi[i]);
    }
    for (int i = tid; i < 8192; i += 256) {
        int ksk = i >> 12, f = (i >> 4) & 255, o = i & 15;
        int col = 32 + ksk * 16 + o;
        int slot = (f >> 3) ^ (col & 7);
        wt[col * 256 + slot * 8 + (f & 7)] = f2bf(wr[i]);
    }

    int row = tid >> 2;
    int kg  = tid & 3;
    int base = blockIdx.x * 64;
    int gr = min(base + row, N_NODES - 1);
    const float* xrow = x + (size_t)gr * F_IN;
    int aslot = kg ^ ((row >> 1) & 3);
    unsigned short* awr0 = &abuf[0][row * 32 + aslot * 8];
    unsigned short* awr1 = &abuf[1][row * 32 + aslot * 8];

    {
        float4 v0 = *reinterpret_cast<const float4*>(xrow + kg * 8);
        float4 v1 = *reinterpret_cast<const float4*>(xrow + kg * 8 + 4);
        u16x8 p;
        p[0] = f2bf(v0.x); p[1] = f2bf(v0.y); p[2] = f2bf(v0.z); p[3] = f2bf(v0.w);
        p[4] = f2bf(v1.x); p[5] = f2bf(v1.y); p[6] = f2bf(v1.z); p[7] = f2bf(v1.w);
        *reinterpret_cast<u16x8*>(awr0) = p;
    }
    __syncthreads();

    int lane = tid & 63;
    int wv   = tid >> 6;
    int arow = wv * 16 + (lane & 15);
    int akg  = lane >> 4;
    const unsigned short* ard0 = &abuf[0][arow * 32 + (akg ^ ((arow >> 1) & 3)) * 8];
    const unsigned short* ard1 = &abuf[1][arow * 32 + (akg ^ ((arow >> 1) & 3)) * 8];
    int col16 = lane & 15;

    f32x4 acc[4] = {{0, 0, 0, 0}, {0, 0, 0, 0}, {0, 0, 0, 0}, {0, 0, 0, 0}};

    for (int ks = 0; ks < 8; ++ks) {
        bf16x8 af = *reinterpret_cast<const bf16x8*>((ks & 1) ? ard1 : ard0);
        bf16x8 bfr[4];
        #pragma unroll
        for (int c = 0; c < 4; ++c) {
            int col = c * 16 + col16;
            int slot = (ks * 4 + akg) ^ (col & 7);
            bfr[c] = *reinterpret_cast<const bf16x8*>(&wt[col * 256 + slot * 8]);
        }
        float4 v0, v1;
        if (ks < 7) {
            v0 = *reinterpret_cast<const float4*>(xrow + (ks + 1) * 32 + kg * 8);
            v1 = *reinterpret_cast<const float4*>(xrow + (ks + 1) * 32 + kg * 8 + 4);
        }
        #pragma unroll
        for (int c = 0; c < 4; ++c)
            acc[c] = __builtin_amdgcn_mfma_f32_16x16x32_bf16(af, bfr[c], acc[c], 0, 0, 0);
        if (ks < 7) {
            u16x8 p;
            p[0] = f2bf(v0.x); p[1] = f2bf(v0.y); p[2] = f2bf(v0.z); p[3] = f2bf(v0.w);
            p[4] = f2bf(v1.x); p[5] = f2bf(v1.y); p[6] = f2bf(v1.z); p[7] = f2bf(v1.w);
            *reinterpret_cast<u16x8*>((ks & 1) ? awr0 : awr1) = p;
        }
        __syncthreads();
    }

    #pragma unroll
    for (int c = 0; c < 4; ++c) {
        #pragma unroll
        for (int r = 0; r < 4; ++r) {
            int n = base + wv * 16 + (lane >> 4) * 4 + r;
            if (n < N_NODES) {
                int col = c * 16 + col16;
                float v = acc[c][r];
                if (col < KH) h1b[(size_t)n * KH + col] = f2bf(v);
                else          r1[(size_t)n * KH + (col - KH)] = v;
            }
        }
    }
}

// ---------------- layer-1 aggregation (LDS) + fused post1 ----------------
__global__ __launch_bounds__(512) void k_agg1(
    const unsigned int* __restrict__ bucketed, const int* __restrict__ gcur,
    const float* __restrict__ dinv, const unsigned short* __restrict__ h1b,
    const float* __restrict__ r1, const float* __restrict__ b1,
    const float* __restrict__ wi2, const float* __restrict__ wr2,
    float* __restrict__ hout, unsigned short* __restrict__ h2b,
    float* __restrict__ r2) {
    __shared__ float aggl[W * 33];      // padded stride 33 -> conflict-light ds_add
    __shared__ float sdinv[W];
    __shared__ float sw[1024];          // wi2 (512) + wr2 (512)
    int tid = threadIdx.x, b = blockIdx.x;
    int nbase = b * W;
    for (int i = tid; i < W * 33; i += 512) aggl[i] = 0.f;
    if (tid < W) sdinv[tid] = (nbase + tid < N_NODES) ? dinv[nbase + tid] : 0.f;
    if (tid < 512) { sw[tid] = wi2[tid]; sw[512 + tid] = wr2[tid]; }
    __syncthreads();

    int cnt = min(gcur[b], CAP);
    const unsigned int* bp = bucketed + (size_t)b * CAP;
    int q = tid & 7;
    for (int base = 0; base < cnt; base += 256) {
        unsigned int p[4]; bool m[4];
        #pragma unroll
        for (int u = 0; u < 4; ++u) {
            int idx = base + u * 64 + (tid >> 3);
            m[u] = idx < cnt;
            p[u] = m[u] ? bp[idx] : 0u;
        }
        float nr[4]; ushort4 v[4];
        #pragma unroll
        for (int u = 0; u < 4; ++u) if (m[u]) {
            int s = p[u] >> W_LOG;
            nr[u] = dinv[s] * sdinv[p[u] & (W - 1)];
            v[u] = *reinterpret_cast<const ushort4*>(h1b + (size_t)s * KH + q * 4);
        }
        #pragma unroll
        for (int u = 0; u < 4; ++u) if (m[u]) {
            float* a = &aggl[(p[u] & (W - 1)) * 33 + q * 4];
            atomicAdd(a + 0, bf2f(v[u].x) * nr[u]);
            atomicAdd(a + 1, bf2f(v[u].y) * nr[u]);
            atomicAdd(a + 2, bf2f(v[u].z) * nr[u]);
            atomicAdd(a + 3, bf2f(v[u].w) * nr[u]);
        }
    }
    __syncthreads();

    // fused post1 tail
    int nd = nbase + tid;
    if (tid < W && nd < N_NODES) {
        float z[KH];
        const float4* r4 = reinterpret_cast<const float4*>(r1 + (size_t)nd * KH);
        #pragma unroll
        for (int qq = 0; qq < 8; ++qq) {
            float4 g = r4[qq];
            z[qq * 4 + 0] = aggl[tid * 33 + qq * 4 + 0] + g.x;
            z[qq * 4 + 1] = aggl[tid * 33 + qq * 4 + 1] + g.y;
            z[qq * 4 + 2] = aggl[tid * 33 + qq * 4 + 2] + g.z;
            z[qq * 4 + 3] = aggl[tid * 33 + qq * 4 + 3] + g.w;
        }
        float h[HID];
        #pragma unroll
        for (int o = 0; o < HID; ++o) {
            float z0 = fmaxf(z[o] + b1[o], 0.f);
            float z1 = fmaxf(z[16 + o] + b1[16 + o], 0.f);
            h[o] = 0.5f * (z0 + z1);
        }
        float4* ho4 = reinterpret_cast<float4*>(hout + (size_t)nd * HID);
        #pragma unroll
        for (int qq = 0; qq < 4; ++qq)
            ho4[qq] = make_float4(h[qq * 4], h[qq * 4 + 1], h[qq * 4 + 2], h[qq * 4 + 3]);
        #pragma unroll
        for (int k = 0; k < 2; ++k) {
            #pragma unroll
            for (int o = 0; o < HID; ++o) {
                float ai = 0.f, ar = 0.f;
                #pragma unroll
                for (int i = 0; i < HID; ++i) {
                    ai += h[i] * sw[k * 256 + i * 16 + o];
                    ar += h[i] * sw[512 + k * 256 + i * 16 + o];
                }
                h2b[(size_t)nd * KH + k * HID + o] = f2bf(ai);
                r2[(size_t)nd * KH + k * HID + o] = ar;
            }
        }
    }
}

// ---------------- layer-2 aggregation (LDS) + fused post2 ----------------
__global__ __launch_bounds__(512) void k_agg2(
    const unsigned int* __restrict__ bucketed, const int* __restrict__ gcur,
    const float* __restrict__ dinv, const unsigned short* __restrict__ h2b,
    const float* __restrict__ r2, const float* __restrict__ b2,
    float* __restrict__ out) {
    __shared__ float aggl[W * 33];
    __shared__ float sdinv[W];
    int tid = threadIdx.x, b = blockIdx.x;
    int nbase = b * W;
    for (int i = tid; i < W * 33; i += 512) aggl[i] = 0.f;
    if (tid < W) sdinv[tid] = (nbase + tid < N_NODES) ? dinv[nbase + tid] : 0.f;
    __syncthreads();

    int cnt = min(gcur[b], CAP);
    const unsigned int* bp = bucketed + (size_t)b * CAP;
    int q = tid & 7;
    for (int base = 0; base < cnt; base += 256) {
        unsigned int p[4]; bool m[4];
        #pragma unroll
        for (int u = 0; u < 4; ++u) {
            int idx = base + u * 64 + (tid >> 3);
            m[u] = idx < cnt;
            p[u] = m[u] ? bp[idx] : 0u;
        }
        float nr[4]; ushort4 v[4];
        #pragma unroll
        for (int u = 0; u < 4; ++u) if (m[u]) {
            int s = p[u] >> W_LOG;
            nr[u] = dinv[s] * sdinv[p[u] & (W - 1)];
            v[u] = *reinterpret_cast<const ushort4*>(h2b + (size_t)s * KH + q * 4);
        }
        #pragma unroll
        for (int u = 0; u < 4; ++u) if (m[u]) {
            float* a = &aggl[(p[u] & (W - 1)) * 33 + q * 4];
            atomicAdd(a + 0, bf2f(v[u].x) * nr[u]);
            atomicAdd(a + 1, bf2f(v[u].y) * nr[u]);
            atomicAdd(a + 2, bf2f(v[u].z) * nr[u]);
            atomicAdd(a + 3, bf2f(v[u].w) * nr[u]);
        }
    }
    __syncthreads();

    // fused post2 tail: mean over stacks + log_softmax
    int nd = nbase + tid;
    if (tid < W && nd < N_NODES) {
        float zz[KH];
        const float4* g4 = reinterpret_cast<const float4*>(r2 + (size_t)nd * KH);
        #pragma unroll
        for (int qq = 0; qq < 8; ++qq) {
            float4 g = g4[qq];
            zz[qq * 4 + 0] = aggl[tid * 33 + qq * 4 + 0] + g.x;
            zz[qq * 4 + 1] = aggl[tid * 33 + qq * 4 + 1] + g.y;
            zz[qq * 4 + 2] = aggl[tid * 33 + qq * 4 + 2] + g.z;
            zz[qq * 4 + 3] = aggl[tid * 33 + qq * 4 + 3] + g.w;
        }
        float z[C_OUT];
        float mx = -1e30f;
        #pragma unroll
        for (int o = 0; o < C_OUT; ++o) {
            z[o] = 0.5f * ((zz[o] + b2[o]) + (zz[16 + o] + b2[16 + o]));
            mx = fmaxf(mx, z[o]);
        }
        float s = 0.f;
        #pragma unroll
        for (int o = 0; o < C_OUT; ++o) s += expf(z[o] - mx);
        float ls = logf(s);
        float4* o4 = reinterpret_cast<float4*>(out + (size_t)nd * C_OUT);
        #pragma unroll
        for (int qq = 0; qq < 4; ++qq)
            o4[qq] = make_float4(z[qq * 4] - mx - ls, z[qq * 4 + 1] - mx - ls,
                                 z[qq * 4 + 2] - mx - ls, z[qq * 4 + 3] - mx - ls);
    }
}

extern "C" void kernel_launch(void* const* d_in, const int* in_sizes, int n_in,
                              void* d_out, int out_size, void* d_ws, size_t ws_size,
                              hipStream_t stream) {
    const float* x   = (const float*)d_in[0];
    const int*   ei  = (const int*)d_in[1];     // [2, E] int32
    const float* wi1 = (const float*)d_in[2];
    const float* wr1 = (const float*)d_in[3];
    const float* b1  = (const float*)d_in[4];
    const float* wi2 = (const float*)d_in[5];
    const float* wr2 = (const float*)d_in[6];
    const float* b2  = (const float*)d_in[7];
    float* out = (float*)d_out;                  // [N*16 log_softmax][N*16 h]

    // ---- workspace layout ----
    int* gcur = (int*)d_ws;                                  // 1024 (NBKT used)
    unsigned int* bucketed = (unsigned int*)(gcur + 1024);   // NBKT*CAP
    float* dinv = (float*)(bucketed + (size_t)NBKT * CAP);   // N
    float* r1   = dinv + N_NODES;                            // 32N
    float* r2   = r1 + (size_t)N_NODES * KH;                 // 32N
    unsigned short* h1b = (unsigned short*)(r2 + (size_t)N_NODES * KH); // 32N u16
    unsigned short* h2b = h1b + (size_t)N_NODES * KH;                   // 32N u16

    const int* srcI = ei;
    const int* dstI = ei + N_EDGES;

    hipMemsetAsync(gcur, 0, 1024 * sizeof(int), stream);

    k_part<<<(N_EDGES + EPB - 1) / EPB, 256, 0, stream>>>(srcI, dstI, gcur, bucketed);
    k_bdeg<<<NBKT, 256, 0, stream>>>(bucketed, gcur, dinv);
    k_gemm1<<<(N_NODES + 63) / 64, 256, 0, stream>>>(x, wi1, wr1, h1b, r1);
    k_agg1<<<NBKT, 512, 0, stream>>>(bucketed, gcur, dinv, h1b, r1, b1, wi2, wr2,
                                     out + (size_t)N_NODES * C_OUT, h2b, r2);
    k_agg2<<<NBKT, 512, 0, stream>>>(bucketed, gcur, dinv, h2b, r2, b2, out);
}

// Round 5
// 411.086 us; speedup vs baseline: 3.8788x; 3.8788x over previous
//
#include <hip/hip_runtime.h>
#include <cstdint>
#include <cstddef>

#define N_NODES 100000
#define N_EDGES 3200000
#define F_IN    256
#define HID     16
#define KH      32      // K stacks (2) * HID (16)
#define C_OUT   16

#define W_LOG   7
#define W       128                     // dst-window (nodes per bucket)
#define NBKT    782                     // ceil(N_NODES / W)
#define CAP     4608                    // bucket capacity (mean 4092, +8 sigma)
#define EPB     4096                    // edges per partition block

typedef short  bf16x8 __attribute__((ext_vector_type(8)));
typedef float  f32x4  __attribute__((ext_vector_type(4)));
typedef unsigned short u16x8 __attribute__((ext_vector_type(8)));

__device__ __forceinline__ unsigned short f2bf(float f) {
    uint32_t u = __builtin_bit_cast(uint32_t, f);
    u += 0x7fffu + ((u >> 16) & 1u);      // round-to-nearest-even
    return (unsigned short)(u >> 16);
}
__device__ __forceinline__ float bf2f(unsigned short s) {
    return __builtin_bit_cast(float, (uint32_t)s << 16);
}

// ---------------- edge partition into dst-window buckets ----------------
// packed = (src << 7) | (dst & 127); bucket = dst >> 7.
__global__ __launch_bounds__(256) void k_part(const int* __restrict__ src,
                                              const int* __restrict__ dst,
                                              int* __restrict__ gcur,
                                              unsigned int* __restrict__ bucketed) {
    __shared__ int hist[NBKT];
    __shared__ int lcur[NBKT];
    __shared__ unsigned int pbuf[EPB];
    __shared__ unsigned short bbuf[EPB];
    int tid = threadIdx.x;
    for (int i = tid; i < NBKT; i += 256) hist[i] = 0;
    __syncthreads();
    int e0 = blockIdx.x * EPB;
    int cnt = min(EPB, N_EDGES - e0);
    for (int i = tid; i < cnt; i += 256) {
        int s = src[e0 + i], d = dst[e0 + i];
        int b = d >> W_LOG;
        pbuf[i] = ((unsigned int)s << W_LOG) | (unsigned int)(d & (W - 1));
        bbuf[i] = (unsigned short)b;
        atomicAdd(&hist[b], 1);
    }
    __syncthreads();
    for (int b = tid; b < NBKT; b += 256) {
        int h = hist[b];
        lcur[b] = h > 0 ? atomicAdd(&gcur[b], h) : 0;
    }
    __syncthreads();
    for (int i = tid; i < cnt; i += 256) {
        int b = bbuf[i];
        int pos = atomicAdd(&lcur[b], 1);
        if (pos < CAP) bucketed[(size_t)b * CAP + pos] = pbuf[i];
    }
}

// ---------------- per-bucket counting sort by dst-low -> CSR + meta + dinv ----------------
__global__ __launch_bounds__(256) void k_sort(const unsigned int* __restrict__ bucketed,
                                              const int* __restrict__ gcur,
                                              int* __restrict__ sorted,
                                              int2* __restrict__ meta,
                                              float* __restrict__ dinv) {
    __shared__ int hist[W], pre[W], cur[W];
    __shared__ int sbuf[CAP];
    int tid = threadIdx.x, b = blockIdx.x;
    int cnt = min(gcur[b], CAP);
    const unsigned int* bp = bucketed + (size_t)b * CAP;
    if (tid < W) hist[tid] = 0;
    __syncthreads();
    for (int i = tid; i < cnt; i += 256) atomicAdd(&hist[bp[i] & (W - 1)], 1);
    __syncthreads();
    if (tid < W) pre[tid] = hist[tid];
    __syncthreads();
    for (int off = 1; off < W; off <<= 1) {
        int v = (tid < W && tid >= off) ? pre[tid - off] : 0;
        __syncthreads();
        if (tid < W) pre[tid] += v;       // inclusive scan
        __syncthreads();
    }
    if (tid < W) cur[tid] = pre[tid] - hist[tid];   // exclusive base
    __syncthreads();
    for (int i = tid; i < cnt; i += 256) {
        unsigned int p = bp[i];
        int pos = atomicAdd(&cur[p & (W - 1)], 1);
        sbuf[pos] = (int)(p >> W_LOG);
    }
    __syncthreads();
    int* so = sorted + (size_t)b * CAP;
    for (int i = tid; i < cnt; i += 256) so[i] = sbuf[i];
    int node = b * W + tid;
    if (tid < W && node < N_NODES) {
        int h = hist[tid];
        meta[node] = make_int2(b * CAP + (pre[tid] - h), h);
        dinv[node] = h > 0 ? rsqrtf((float)h) : 0.f;
    }
}

// ---------------- layer-1 GEMM via bf16 MFMA ----------------
// C[100000 x 64] = x @ W; cols 0..15 -> h1s0 (bf16, *dinv), 16..31 -> h1s1 (bf16, *dinv),
// 32..63 -> r1 (f32, unscaled).
__global__ __launch_bounds__(256) void k_gemm1(
    const float* __restrict__ x, const float* __restrict__ wi,
    const float* __restrict__ wr, const float* __restrict__ dinv,
    unsigned short* __restrict__ h1s0, unsigned short* __restrict__ h1s1,
    float* __restrict__ r1) {
    __shared__ unsigned short wt[64 * 256];     // 32KB  W^T: [col][k] bf16, slot-swizzled
    __shared__ unsigned short abuf[2][64 * 32]; // 8KB   A: [row][k] bf16, slot-swizzled

    int tid = threadIdx.x;

    for (int i = tid; i < 8192; i += 256) {
        int ksk = i >> 12, f = (i >> 4) & 255, o = i & 15;
        int col = ksk * 16 + o;
        int slot = (f >> 3) ^ (col & 7);
        wt[col * 256 + slot * 8 + (f & 7)] = f2bf(wi[i]);
    }
    for (int i = tid; i < 8192; i += 256) {
        int ksk = i >> 12, f = (i >> 4) & 255, o = i & 15;
        int col = 32 + ksk * 16 + o;
        int slot = (f >> 3) ^ (col & 7);
        wt[col * 256 + slot * 8 + (f & 7)] = f2bf(wr[i]);
    }

    int row = tid >> 2;
    int kg  = tid & 3;
    int base = blockIdx.x * 64;
    int gr = min(base + row, N_NODES - 1);
    const float* xrow = x + (size_t)gr * F_IN;
    int aslot = kg ^ ((row >> 1) & 3);
    unsigned short* awr0 = &abuf[0][row * 32 + aslot * 8];
    unsigned short* awr1 = &abuf[1][row * 32 + aslot * 8];

    {
        float4 v0 = *reinterpret_cast<const float4*>(xrow + kg * 8);
        float4 v1 = *reinterpret_cast<const float4*>(xrow + kg * 8 + 4);
        u16x8 p;
        p[0] = f2bf(v0.x); p[1] = f2bf(v0.y); p[2] = f2bf(v0.z); p[3] = f2bf(v0.w);
        p[4] = f2bf(v1.x); p[5] = f2bf(v1.y); p[6] = f2bf(v1.z); p[7] = f2bf(v1.w);
        *reinterpret_cast<u16x8*>(awr0) = p;
    }
    __syncthreads();

    int lane = tid & 63;
    int wv   = tid >> 6;
    int arow = wv * 16 + (lane & 15);
    int akg  = lane >> 4;
    const unsigned short* ard0 = &abuf[0][arow * 32 + (akg ^ ((arow >> 1) & 3)) * 8];
    const unsigned short* ard1 = &abuf[1][arow * 32 + (akg ^ ((arow >> 1) & 3)) * 8];
    int col16 = lane & 15;

    f32x4 acc[4] = {{0, 0, 0, 0}, {0, 0, 0, 0}, {0, 0, 0, 0}, {0, 0, 0, 0}};

    for (int ks = 0; ks < 8; ++ks) {
        bf16x8 af = *reinterpret_cast<const bf16x8*>((ks & 1) ? ard1 : ard0);
        bf16x8 bfr[4];
        #pragma unroll
        for (int c = 0; c < 4; ++c) {
            int col = c * 16 + col16;
            int slot = (ks * 4 + akg) ^ (col & 7);
            bfr[c] = *reinterpret_cast<const bf16x8*>(&wt[col * 256 + slot * 8]);
        }
        float4 v0, v1;
        if (ks < 7) {
            v0 = *reinterpret_cast<const float4*>(xrow + (ks + 1) * 32 + kg * 8);
            v1 = *reinterpret_cast<const float4*>(xrow + (ks + 1) * 32 + kg * 8 + 4);
        }
        #pragma unroll
        for (int c = 0; c < 4; ++c)
            acc[c] = __builtin_amdgcn_mfma_f32_16x16x32_bf16(af, bfr[c], acc[c], 0, 0, 0);
        if (ks < 7) {
            u16x8 p;
            p[0] = f2bf(v0.x); p[1] = f2bf(v0.y); p[2] = f2bf(v0.z); p[3] = f2bf(v0.w);
            p[4] = f2bf(v1.x); p[5] = f2bf(v1.y); p[6] = f2bf(v1.z); p[7] = f2bf(v1.w);
            *reinterpret_cast<u16x8*>((ks & 1) ? awr0 : awr1) = p;
        }
        __syncthreads();
    }

    // D layout: col = lane&15, row = (lane>>4)*4 + reg
    float dv[4];
    #pragma unroll
    for (int r = 0; r < 4; ++r) {
        int n = base + wv * 16 + (lane >> 4) * 4 + r;
        dv[r] = (n < N_NODES) ? dinv[n] : 0.f;
    }
    #pragma unroll
    for (int c = 0; c < 4; ++c) {
        #pragma unroll
        for (int r = 0; r < 4; ++r) {
            int n = base + wv * 16 + (lane >> 4) * 4 + r;
            if (n < N_NODES) {
                int col = c * 16 + col16;
                float v = acc[c][r];
                if (col < 16)      h1s0[(size_t)n * HID + col] = f2bf(v * dv[r]);
                else if (col < 32) h1s1[(size_t)n * HID + (col - 16)] = f2bf(v * dv[r]);
                else               r1[(size_t)n * KH + (col - 32)] = v;
            }
        }
    }
}

// ---------------- CSR gather: agg[n] = dinv[n] * sum_{e} tab[src_e]  ----------------
// tab rows pre-scaled by dinv[src]; 4 threads/node, 8B (4 cols bf16) each; no atomics.
__global__ __launch_bounds__(256) void k_gath(
    const int* __restrict__ sorted, const int2* __restrict__ meta,
    const float* __restrict__ dinv, const unsigned short* __restrict__ tab,
    float* __restrict__ agg) {
    int t = blockIdx.x * 256 + threadIdx.x;
    int n = t >> 2, q = t & 3;
    if (n >= N_NODES) return;
    int2 m = meta[n];
    const int* sp = sorted + m.x;
    float ax = 0, ay = 0, az = 0, aw = 0;
    int j = 0;
    for (; j + 4 <= m.y; j += 4) {
        int s0 = sp[j], s1 = sp[j + 1], s2 = sp[j + 2], s3 = sp[j + 3];
        ushort4 v0 = *reinterpret_cast<const ushort4*>(tab + (size_t)s0 * HID + q * 4);
        ushort4 v1 = *reinterpret_cast<const ushort4*>(tab + (size_t)s1 * HID + q * 4);
        ushort4 v2 = *reinterpret_cast<const ushort4*>(tab + (size_t)s2 * HID + q * 4);
        ushort4 v3 = *reinterpret_cast<const ushort4*>(tab + (size_t)s3 * HID + q * 4);
        ax += (bf2f(v0.x) + bf2f(v1.x)) + (bf2f(v2.x) + bf2f(v3.x));
        ay += (bf2f(v0.y) + bf2f(v1.y)) + (bf2f(v2.y) + bf2f(v3.y));
        az += (bf2f(v0.z) + bf2f(v1.z)) + (bf2f(v2.z) + bf2f(v3.z));
        aw += (bf2f(v0.w) + bf2f(v1.w)) + (bf2f(v2.w) + bf2f(v3.w));
    }
    for (; j < m.y; ++j) {
        int s0 = sp[j];
        ushort4 v0 = *reinterpret_cast<const ushort4*>(tab + (size_t)s0 * HID + q * 4);
        ax += bf2f(v0.x); ay += bf2f(v0.y); az += bf2f(v0.z); aw += bf2f(v0.w);
    }
    float dn = dinv[n];
    *reinterpret_cast<float4*>(agg + (size_t)n * HID + q * 4) =
        make_float4(ax * dn, ay * dn, az * dn, aw * dn);
}

// ---------------- post layer-1: act + mean + layer-2 projections ----------------
__global__ void k_post1(const float* __restrict__ agg1a, const float* __restrict__ agg1b,
                        const float* __restrict__ r1, const float* __restrict__ b1,
                        const float* __restrict__ wi2, const float* __restrict__ wr2,
                        const float* __restrict__ dinv,
                        float* __restrict__ hout, unsigned short* __restrict__ h2s0,
                        unsigned short* __restrict__ h2s1, float* __restrict__ r2) {
    int n = blockIdx.x * blockDim.x + threadIdx.x;
    if (n >= N_NODES) return;
    const float4* aa = reinterpret_cast<const float4*>(agg1a + (size_t)n * HID);
    const float4* ab = reinterpret_cast<const float4*>(agg1b + (size_t)n * HID);
    const float4* r4 = reinterpret_cast<const float4*>(r1 + (size_t)n * KH);
    float z[KH];
    #pragma unroll
    for (int qq = 0; qq < 4; ++qq) {
        float4 a0 = aa[qq], a1 = ab[qq], g0 = r4[qq], g1 = r4[4 + qq];
        z[qq * 4 + 0] = a0.x + g0.x;  z[qq * 4 + 1] = a0.y + g0.y;
        z[qq * 4 + 2] = a0.z + g0.z;  z[qq * 4 + 3] = a0.w + g0.w;
        z[16 + qq * 4 + 0] = a1.x + g1.x;  z[16 + qq * 4 + 1] = a1.y + g1.y;
        z[16 + qq * 4 + 2] = a1.z + g1.z;  z[16 + qq * 4 + 3] = a1.w + g1.w;
    }
    float h[HID];
    #pragma unroll
    for (int o = 0; o < HID; ++o) {
        float z0 = fmaxf(z[o] + b1[o], 0.f);
        float z1 = fmaxf(z[16 + o] + b1[16 + o], 0.f);
        h[o] = 0.5f * (z0 + z1);
    }
    float4* ho4 = reinterpret_cast<float4*>(hout + (size_t)n * HID);
    #pragma unroll
    for (int qq = 0; qq < 4; ++qq)
        ho4[qq] = make_float4(h[qq * 4], h[qq * 4 + 1], h[qq * 4 + 2], h[qq * 4 + 3]);
    float dn = dinv[n];
    #pragma unroll
    for (int k = 0; k < 2; ++k) {
        #pragma unroll
        for (int o = 0; o < HID; ++o) {
            float ai = 0.f, ar = 0.f;
            #pragma unroll
            for (int i = 0; i < HID; ++i) {
                ai += h[i] * wi2[k * 256 + i * 16 + o];
                ar += h[i] * wr2[k * 256 + i * 16 + o];
            }
            if (k == 0) h2s0[(size_t)n * HID + o] = f2bf(ai * dn);
            else        h2s1[(size_t)n * HID + o] = f2bf(ai * dn);
            r2[(size_t)n * KH + k * HID + o] = ar;
        }
    }
}

// ---------------- post layer-2: mean + log_softmax ----------------
__global__ void k_post2(const float* __restrict__ agg2a, const float* __restrict__ agg2b,
                        const float* __restrict__ r2, const float* __restrict__ b2,
                        float* __restrict__ out) {
    int n = blockIdx.x * blockDim.x + threadIdx.x;
    if (n >= N_NODES) return;
    const float4* aa = reinterpret_cast<const float4*>(agg2a + (size_t)n * HID);
    const float4* ab = reinterpret_cast<const float4*>(agg2b + (size_t)n * HID);
    const float4* g4 = reinterpret_cast<const float4*>(r2 + (size_t)n * KH);
    float zz[KH];
    #pragma unroll
    for (int qq = 0; qq < 4; ++qq) {
        float4 a0 = aa[qq], a1 = ab[qq], g0 = g4[qq], g1 = g4[4 + qq];
        zz[qq * 4 + 0] = a0.x + g0.x;  zz[qq * 4 + 1] = a0.y + g0.y;
        zz[qq * 4 + 2] = a0.z + g0.z;  zz[qq * 4 + 3] = a0.w + g0.w;
        zz[16 + qq * 4 + 0] = a1.x + g1.x;  zz[16 + qq * 4 + 1] = a1.y + g1.y;
        zz[16 + qq * 4 + 2] = a1.z + g1.z;  zz[16 + qq * 4 + 3] = a1.w + g1.w;
    }
    float z[C_OUT];
    float mx = -1e30f;
    #pragma unroll
    for (int o = 0; o < C_OUT; ++o) {
        z[o] = 0.5f * ((zz[o] + b2[o]) + (zz[16 + o] + b2[16 + o]));
        mx = fmaxf(mx, z[o]);
    }
    float s = 0.f;
    #pragma unroll
    for (int o = 0; o < C_OUT; ++o) s += expf(z[o] - mx);
    float ls = logf(s);
    float4* o4 = reinterpret_cast<float4*>(out + (size_t)n * C_OUT);
    #pragma unroll
    for (int qq = 0; qq < 4; ++qq)
        o4[qq] = make_float4(z[qq * 4] - mx - ls, z[qq * 4 + 1] - mx - ls,
                             z[qq * 4 + 2] - mx - ls, z[qq * 4 + 3] - mx - ls);
}

extern "C" void kernel_launch(void* const* d_in, const int* in_sizes, int n_in,
                              void* d_out, int out_size, void* d_ws, size_t ws_size,
                              hipStream_t stream) {
    const float* x   = (const float*)d_in[0];
    const int*   ei  = (const int*)d_in[1];     // [2, E] int32
    const float* wi1 = (const float*)d_in[2];
    const float* wr1 = (const float*)d_in[3];
    const float* b1  = (const float*)d_in[4];
    const float* wi2 = (const float*)d_in[5];
    const float* wr2 = (const float*)d_in[6];
    const float* b2  = (const float*)d_in[7];
    float* out = (float*)d_out;                  // [N*16 log_softmax][N*16 h]

    // ---- workspace layout ----
    int* gcur = (int*)d_ws;                                      // 1024
    unsigned int* bucketed = (unsigned int*)(gcur + 1024);       // NBKT*CAP
    int* sorted = (int*)(bucketed + (size_t)NBKT * CAP);         // NBKT*CAP
    int2* meta  = (int2*)(sorted + (size_t)NBKT * CAP);          // N (8B aligned)
    float* dinv = (float*)(meta + N_NODES);                      // N
    float* r1   = dinv + N_NODES;                                // 32N
    float* r2   = r1 + (size_t)N_NODES * KH;                     // 32N
    float* agg1a = r2 + (size_t)N_NODES * KH;                    // 16N
    float* agg1b = agg1a + (size_t)N_NODES * HID;                // 16N
    unsigned short* h1s0 = (unsigned short*)(agg1b + (size_t)N_NODES * HID); // 16N u16
    unsigned short* h1s1 = h1s0 + (size_t)N_NODES * HID;                     // 16N u16
    // aliases (sequential stream makes these safe):
    float* agg2a = agg1a;           // agg1 consumed by post1 before gath2 writes
    float* agg2b = agg1b;
    unsigned short* h2s0 = h1s0;    // h1 tables consumed by gath1 before post1 writes
    unsigned short* h2s1 = h1s1;

    const int* srcI = ei;
    const int* dstI = ei + N_EDGES;

    hipMemsetAsync(gcur, 0, 1024 * sizeof(int), stream);

    k_part<<<(N_EDGES + EPB - 1) / EPB, 256, 0, stream>>>(srcI, dstI, gcur, bucketed);
    k_sort<<<NBKT, 256, 0, stream>>>(bucketed, gcur, sorted, meta, dinv);
    k_gemm1<<<(N_NODES + 63) / 64, 256, 0, stream>>>(x, wi1, wr1, dinv, h1s0, h1s1, r1);
    int gathGrid = (N_NODES * 4 + 255) / 256;
    k_gath<<<gathGrid, 256, 0, stream>>>(sorted, meta, dinv, h1s0, agg1a);
    k_gath<<<gathGrid, 256, 0, stream>>>(sorted, meta, dinv, h1s1, agg1b);
    k_post1<<<(N_NODES + 255) / 256, 256, 0, stream>>>(agg1a, agg1b, r1, b1, wi2, wr2,
                                                       dinv, out + (size_t)N_NODES * C_OUT,
                                                       h2s0, h2s1, r2);
    k_gath<<<gathGrid, 256, 0, stream>>>(sorted, meta, dinv, h2s0, agg2a);
    k_gath<<<gathGrid, 256, 0, stream>>>(sorted, meta, dinv, h2s1, agg2b);
    k_post2<<<(N_NODES + 255) / 256, 256, 0, stream>>>(agg2a, agg2b, r2, b2, out);
}

// Round 6
// 383.157 us; speedup vs baseline: 4.1615x; 1.0729x over previous
//
#include <hip/hip_runtime.h>
#include <cstdint>
#include <cstddef>

#define N_NODES 100000
#define N_EDGES 3200000
#define F_IN    256
#define HID     16
#define KH      32      // K stacks (2) * HID (16)
#define C_OUT   16

#define W_LOG   7
#define W       128                     // dst-window (nodes per bucket)
#define NBKT    782                     // ceil(N_NODES / W)
#define CAP     4608                    // bucket capacity (mean 4092, +8 sigma)
#define EPB     4096                    // edges per partition block

typedef short  bf16x8 __attribute__((ext_vector_type(8)));
typedef float  f32x4  __attribute__((ext_vector_type(4)));
typedef unsigned short u16x8 __attribute__((ext_vector_type(8)));

__device__ __forceinline__ unsigned short f2bf(float f) {
    uint32_t u = __builtin_bit_cast(uint32_t, f);
    u += 0x7fffu + ((u >> 16) & 1u);      // round-to-nearest-even
    return (unsigned short)(u >> 16);
}
__device__ __forceinline__ float bf2f(unsigned short s) {
    return __builtin_bit_cast(float, (uint32_t)s << 16);
}

// ---------------- edge partition into dst-window buckets ----------------
__global__ __launch_bounds__(256) void k_part(const int* __restrict__ src,
                                              const int* __restrict__ dst,
                                              int* __restrict__ gcur,
                                              unsigned int* __restrict__ bucketed) {
    __shared__ int hist[NBKT];
    __shared__ int lcur[NBKT];
    __shared__ unsigned int pbuf[EPB];
    __shared__ unsigned short bbuf[EPB];
    int tid = threadIdx.x;
    for (int i = tid; i < NBKT; i += 256) hist[i] = 0;
    __syncthreads();
    int e0 = blockIdx.x * EPB;
    int cnt = min(EPB, N_EDGES - e0);
    for (int i = tid; i < cnt; i += 256) {
        int s = src[e0 + i], d = dst[e0 + i];
        int b = d >> W_LOG;
        pbuf[i] = ((unsigned int)s << W_LOG) | (unsigned int)(d & (W - 1));
        bbuf[i] = (unsigned short)b;
        atomicAdd(&hist[b], 1);
    }
    __syncthreads();
    for (int b = tid; b < NBKT; b += 256) {
        int h = hist[b];
        lcur[b] = h > 0 ? atomicAdd(&gcur[b], h) : 0;
    }
    __syncthreads();
    for (int i = tid; i < cnt; i += 256) {
        int b = bbuf[i];
        int pos = atomicAdd(&lcur[b], 1);
        if (pos < CAP) bucketed[(size_t)b * CAP + pos] = pbuf[i];
    }
}

// ---------------- per-bucket counting sort by dst-low -> CSR + meta + dinv ----------------
__global__ __launch_bounds__(256) void k_sort(const unsigned int* __restrict__ bucketed,
                                              const int* __restrict__ gcur,
                                              int* __restrict__ sorted,
                                              int2* __restrict__ meta,
                                              float* __restrict__ dinv) {
    __shared__ int hist[W], pre[W], cur[W];
    __shared__ int sbuf[CAP];
    int tid = threadIdx.x, b = blockIdx.x;
    int cnt = min(gcur[b], CAP);
    const unsigned int* bp = bucketed + (size_t)b * CAP;
    if (tid < W) hist[tid] = 0;
    __syncthreads();
    for (int i = tid; i < cnt; i += 256) atomicAdd(&hist[bp[i] & (W - 1)], 1);
    __syncthreads();
    if (tid < W) pre[tid] = hist[tid];
    __syncthreads();
    for (int off = 1; off < W; off <<= 1) {
        int v = (tid < W && tid >= off) ? pre[tid - off] : 0;
        __syncthreads();
        if (tid < W) pre[tid] += v;       // inclusive scan
        __syncthreads();
    }
    if (tid < W) cur[tid] = pre[tid] - hist[tid];   // exclusive base
    __syncthreads();
    for (int i = tid; i < cnt; i += 256) {
        unsigned int p = bp[i];
        int pos = atomicAdd(&cur[p & (W - 1)], 1);
        sbuf[pos] = (int)(p >> W_LOG);
    }
    __syncthreads();
    int* so = sorted + (size_t)b * CAP;
    for (int i = tid; i < cnt; i += 256) so[i] = sbuf[i];
    int node = b * W + tid;
    if (tid < W && node < N_NODES) {
        int h = hist[tid];
        meta[node] = make_int2(b * CAP + (pre[tid] - h), h);
        dinv[node] = h > 0 ? rsqrtf((float)h) : 0.f;
    }
}

// ---------------- layer-1 GEMM via bf16 MFMA, direct-to-register A ----------------
// C[100000 x 64] = x @ W; cols 0..15 -> h1s0 (bf16, *dinv), 16..31 -> h1s1 (bf16, *dinv),
// 32..63 -> r1 (f32, unscaled). 512 thr = 8 waves x 16 rows; no A staging, no barriers.
__global__ __launch_bounds__(512) void k_gemm1(
    const float* __restrict__ x, const float* __restrict__ wi,
    const float* __restrict__ wr, const float* __restrict__ dinv,
    unsigned short* __restrict__ h1s0, unsigned short* __restrict__ h1s1,
    float* __restrict__ r1) {
    __shared__ unsigned short wt[64 * 256];     // 32KB  W^T: [col][k] bf16, slot-swizzled
    int tid = threadIdx.x;

    for (int i = tid; i < 8192; i += 512) {
        int ksk = i >> 12, f = (i >> 4) & 255, o = i & 15;
        int col = ksk * 16 + o;
        int slot = (f >> 3) ^ (col & 7);
        wt[col * 256 + slot * 8 + (f & 7)] = f2bf(wi[i]);
    }
    for (int i = tid; i < 8192; i += 512) {
        int ksk = i >> 12, f = (i >> 4) & 255, o = i & 15;
        int col = 32 + ksk * 16 + o;
        int slot = (f >> 3) ^ (col & 7);
        wt[col * 256 + slot * 8 + (f & 7)] = f2bf(wr[i]);
    }
    __syncthreads();

    int lane = tid & 63;
    int wv   = tid >> 6;                        // wave 0..7
    int base = blockIdx.x * 128 + wv * 16;      // 16 rows per wave
    int row16 = lane & 15;
    int akg   = lane >> 4;                      // A k-group 0..3
    int gr = min(base + row16, N_NODES - 1);
    const float* xp = x + (size_t)gr * F_IN + akg * 8;

    f32x4 acc[4] = {{0, 0, 0, 0}, {0, 0, 0, 0}, {0, 0, 0, 0}, {0, 0, 0, 0}};

    #pragma unroll
    for (int ks = 0; ks < 8; ++ks) {
        float4 v0 = *reinterpret_cast<const float4*>(xp + ks * 32);
        float4 v1 = *reinterpret_cast<const float4*>(xp + ks * 32 + 4);
        u16x8 p;
        p[0] = f2bf(v0.x); p[1] = f2bf(v0.y); p[2] = f2bf(v0.z); p[3] = f2bf(v0.w);
        p[4] = f2bf(v1.x); p[5] = f2bf(v1.y); p[6] = f2bf(v1.z); p[7] = f2bf(v1.w);
        bf16x8 af = __builtin_bit_cast(bf16x8, p);
        #pragma unroll
        for (int c = 0; c < 4; ++c) {
            int col = c * 16 + row16;
            int slot = (ks * 4 + akg) ^ (col & 7);
            bf16x8 bfr = *reinterpret_cast<const bf16x8*>(&wt[col * 256 + slot * 8]);
            acc[c] = __builtin_amdgcn_mfma_f32_16x16x32_bf16(af, bfr, acc[c], 0, 0, 0);
        }
    }

    // D layout: col = lane&15, row = (lane>>4)*4 + reg
    float dv[4];
    #pragma unroll
    for (int r = 0; r < 4; ++r) {
        int n = base + (lane >> 4) * 4 + r;
        dv[r] = (n < N_NODES) ? dinv[n] : 0.f;
    }
    #pragma unroll
    for (int c = 0; c < 4; ++c) {
        #pragma unroll
        for (int r = 0; r < 4; ++r) {
            int n = base + (lane >> 4) * 4 + r;
            if (n < N_NODES) {
                int col = c * 16 + row16;
                float v = acc[c][r];
                if (col < 16)      h1s0[(size_t)n * HID + col] = f2bf(v * dv[r]);
                else if (col < 32) h1s1[(size_t)n * HID + (col - 16)] = f2bf(v * dv[r]);
                else               r1[(size_t)n * KH + (col - 32)] = v;
            }
        }
    }
}

// ---------------- CSR gather: agg[n] = dinv[n] * sum_{e} tab[src_e]  ----------------
__global__ __launch_bounds__(256) void k_gath(
    const int* __restrict__ sorted, const int2* __restrict__ meta,
    const float* __restrict__ dinv, const unsigned short* __restrict__ tab,
    float* __restrict__ agg) {
    int t = blockIdx.x * 256 + threadIdx.x;
    int n = t >> 2, q = t & 3;
    if (n >= N_NODES) return;
    int2 m = meta[n];
    const int* sp = sorted + m.x;
    float ax = 0, ay = 0, az = 0, aw = 0;
    int j = 0;
    for (; j + 4 <= m.y; j += 4) {
        int s0 = sp[j], s1 = sp[j + 1], s2 = sp[j + 2], s3 = sp[j + 3];
        ushort4 v0 = *reinterpret_cast<const ushort4*>(tab + (size_t)s0 * HID + q * 4);
        ushort4 v1 = *reinterpret_cast<const ushort4*>(tab + (size_t)s1 * HID + q * 4);
        ushort4 v2 = *reinterpret_cast<const ushort4*>(tab + (size_t)s2 * HID + q * 4);
        ushort4 v3 = *reinterpret_cast<const ushort4*>(tab + (size_t)s3 * HID + q * 4);
        ax += (bf2f(v0.x) + bf2f(v1.x)) + (bf2f(v2.x) + bf2f(v3.x));
        ay += (bf2f(v0.y) + bf2f(v1.y)) + (bf2f(v2.y) + bf2f(v3.y));
        az += (bf2f(v0.z) + bf2f(v1.z)) + (bf2f(v2.z) + bf2f(v3.z));
        aw += (bf2f(v0.w) + bf2f(v1.w)) + (bf2f(v2.w) + bf2f(v3.w));
    }
    for (; j < m.y; ++j) {
        int s0 = sp[j];
        ushort4 v0 = *reinterpret_cast<const ushort4*>(tab + (size_t)s0 * HID + q * 4);
        ax += bf2f(v0.x); ay += bf2f(v0.y); az += bf2f(v0.z); aw += bf2f(v0.w);
    }
    float dn = dinv[n];
    *reinterpret_cast<float4*>(agg + (size_t)n * HID + q * 4) =
        make_float4(ax * dn, ay * dn, az * dn, aw * dn);
}

// ---------------- post layer-1: act + stack-mean + collapsed layer-2 projections ----
// Layer 2 is linear before its stack-mean, so it collapses to mean weights:
// out_pre = S.(h @ Wi2m) + h @ Wr2m + b2m,  Wi2m = mean_k wi2[k], etc.
__global__ void k_post1(const float* __restrict__ agg1a, const float* __restrict__ agg1b,
                        const float* __restrict__ r1, const float* __restrict__ b1,
                        const float* __restrict__ wi2, const float* __restrict__ wr2,
                        const float* __restrict__ dinv,
                        float* __restrict__ hout, unsigned short* __restrict__ h2t,
                        float* __restrict__ r2m) {
    int n = blockIdx.x * blockDim.x + threadIdx.x;
    if (n >= N_NODES) return;
    const float4* aa = reinterpret_cast<const float4*>(agg1a + (size_t)n * HID);
    const float4* ab = reinterpret_cast<const float4*>(agg1b + (size_t)n * HID);
    const float4* r4 = reinterpret_cast<const float4*>(r1 + (size_t)n * KH);
    float z[KH];
    #pragma unroll
    for (int qq = 0; qq < 4; ++qq) {
        float4 a0 = aa[qq], a1 = ab[qq], g0 = r4[qq], g1 = r4[4 + qq];
        z[qq * 4 + 0] = a0.x + g0.x;  z[qq * 4 + 1] = a0.y + g0.y;
        z[qq * 4 + 2] = a0.z + g0.z;  z[qq * 4 + 3] = a0.w + g0.w;
        z[16 + qq * 4 + 0] = a1.x + g1.x;  z[16 + qq * 4 + 1] = a1.y + g1.y;
        z[16 + qq * 4 + 2] = a1.z + g1.z;  z[16 + qq * 4 + 3] = a1.w + g1.w;
    }
    float h[HID];
    #pragma unroll
    for (int o = 0; o < HID; ++o) {
        float z0 = fmaxf(z[o] + b1[o], 0.f);
        float z1 = fmaxf(z[16 + o] + b1[16 + o], 0.f);
        h[o] = 0.5f * (z0 + z1);
    }
    float4* ho4 = reinterpret_cast<float4*>(hout + (size_t)n * HID);
    #pragma unroll
    for (int qq = 0; qq < 4; ++qq)
        ho4[qq] = make_float4(h[qq * 4], h[qq * 4 + 1], h[qq * 4 + 2], h[qq * 4 + 3]);
    float dn = dinv[n];
    #pragma unroll
    for (int o = 0; o < HID; ++o) {
        float ai = 0.f, ar = 0.f;
        #pragma unroll
        for (int i = 0; i < HID; ++i) {
            float wim = 0.5f * (wi2[i * 16 + o] + wi2[256 + i * 16 + o]);
            float wrm = 0.5f * (wr2[i * 16 + o] + wr2[256 + i * 16 + o]);
            ai += h[i] * wim;
            ar += h[i] * wrm;
        }
        h2t[(size_t)n * HID + o] = f2bf(ai * dn);
        r2m[(size_t)n * HID + o] = ar;
    }
}

// ---------------- post layer-2: add root + bias-mean + log_softmax ----------------
__global__ void k_post2(const float* __restrict__ agg2, const float* __restrict__ r2m,
                        const float* __restrict__ b2, float* __restrict__ out) {
    int n = blockIdx.x * blockDim.x + threadIdx.x;
    if (n >= N_NODES) return;
    const float4* aa = reinterpret_cast<const float4*>(agg2 + (size_t)n * HID);
    const float4* g4 = reinterpret_cast<const float4*>(r2m + (size_t)n * HID);
    float z[C_OUT];
    float mx = -1e30f;
    #pragma unroll
    for (int qq = 0; qq < 4; ++qq) {
        float4 a = aa[qq], g = g4[qq];
        z[qq * 4 + 0] = a.x + g.x;  z[qq * 4 + 1] = a.y + g.y;
        z[qq * 4 + 2] = a.z + g.z;  z[qq * 4 + 3] = a.w + g.w;
    }
    #pragma unroll
    for (int o = 0; o < C_OUT; ++o) {
        z[o] += 0.5f * (b2[o] + b2[16 + o]);
        mx = fmaxf(mx, z[o]);
    }
    float s = 0.f;
    #pragma unroll
    for (int o = 0; o < C_OUT; ++o) s += expf(z[o] - mx);
    float ls = logf(s);
    float4* o4 = reinterpret_cast<float4*>(out + (size_t)n * C_OUT);
    #pragma unroll
    for (int qq = 0; qq < 4; ++qq)
        o4[qq] = make_float4(z[qq * 4] - mx - ls, z[qq * 4 + 1] - mx - ls,
                             z[qq * 4 + 2] - mx - ls, z[qq * 4 + 3] - mx - ls);
}

extern "C" void kernel_launch(void* const* d_in, const int* in_sizes, int n_in,
                              void* d_out, int out_size, void* d_ws, size_t ws_size,
                              hipStream_t stream) {
    const float* x   = (const float*)d_in[0];
    const int*   ei  = (const int*)d_in[1];     // [2, E] int32
    const float* wi1 = (const float*)d_in[2];
    const float* wr1 = (const float*)d_in[3];
    const float* b1  = (const float*)d_in[4];
    const float* wi2 = (const float*)d_in[5];
    const float* wr2 = (const float*)d_in[6];
    const float* b2  = (const float*)d_in[7];
    float* out = (float*)d_out;                  // [N*16 log_softmax][N*16 h]

    // ---- workspace layout ----
    int* gcur = (int*)d_ws;                                      // 1024
    unsigned int* bucketed = (unsigned int*)(gcur + 1024);       // NBKT*CAP
    int* sorted = (int*)(bucketed + (size_t)NBKT * CAP);         // NBKT*CAP
    int2* meta  = (int2*)(sorted + (size_t)NBKT * CAP);          // N
    float* dinv = (float*)(meta + N_NODES);                      // N
    float* r1   = dinv + N_NODES;                                // 32N
    float* r2m  = r1 + (size_t)N_NODES * KH;                     // 16N
    float* agg1a = r2m + (size_t)N_NODES * HID;                  // 16N
    float* agg1b = agg1a + (size_t)N_NODES * HID;                // 16N
    unsigned short* h1s0 = (unsigned short*)(agg1b + (size_t)N_NODES * HID); // 16N u16
    unsigned short* h1s1 = h1s0 + (size_t)N_NODES * HID;                     // 16N u16
    // aliases (sequential stream makes these safe):
    float* agg2 = agg1a;            // agg1 consumed by post1 before gath2 writes
    unsigned short* h2t = h1s0;     // h1 tables consumed by gath1 before post1 writes

    const int* srcI = ei;
    const int* dstI = ei + N_EDGES;

    hipMemsetAsync(gcur, 0, 1024 * sizeof(int), stream);

    k_part<<<(N_EDGES + EPB - 1) / EPB, 256, 0, stream>>>(srcI, dstI, gcur, bucketed);
    k_sort<<<NBKT, 256, 0, stream>>>(bucketed, gcur, sorted, meta, dinv);
    k_gemm1<<<(N_NODES + 127) / 128, 512, 0, stream>>>(x, wi1, wr1, dinv, h1s0, h1s1, r1);
    int gathGrid = (N_NODES * 4 + 255) / 256;
    k_gath<<<gathGrid, 256, 0, stream>>>(sorted, meta, dinv, h1s0, agg1a);
    k_gath<<<gathGrid, 256, 0, stream>>>(sorted, meta, dinv, h1s1, agg1b);
    k_post1<<<(N_NODES + 255) / 256, 256, 0, stream>>>(agg1a, agg1b, r1, b1, wi2, wr2,
                                                       dinv, out + (size_t)N_NODES * C_OUT,
                                                       h2t, r2m);
    k_gath<<<gathGrid, 256, 0, stream>>>(sorted, meta, dinv, h2t, agg2);
    k_post2<<<(N_NODES + 255) / 256, 256, 0, stream>>>(agg2, r2m, b2, out);
}

// Round 7
// 331.737 us; speedup vs baseline: 4.8065x; 1.1550x over previous
//
#include <hip/hip_runtime.h>
#include <cstdint>
#include <cstddef>

#define N_NODES 100000
#define N_EDGES 3200000
#define F_IN    256
#define HID     16
#define KH      32      // K stacks (2) * HID (16)
#define C_OUT   16

#define W_LOG   7
#define W       128                     // dst-window (nodes per bucket)
#define NBKT    782                     // ceil(N_NODES / W)
#define CAP     4608                    // bucket capacity (mean 4092, +8 sigma)
#define EPB     4096                    // edges per partition block

typedef short  bf16x8 __attribute__((ext_vector_type(8)));
typedef float  f32x4  __attribute__((ext_vector_type(4)));
typedef unsigned short u16x8 __attribute__((ext_vector_type(8)));

__device__ __forceinline__ unsigned short f2bf(float f) {
    uint32_t u = __builtin_bit_cast(uint32_t, f);
    u += 0x7fffu + ((u >> 16) & 1u);      // round-to-nearest-even
    return (unsigned short)(u >> 16);
}
__device__ __forceinline__ float bf2f(unsigned short s) {
    return __builtin_bit_cast(float, (uint32_t)s << 16);
}

// ---------------- edge partition into dst-window buckets ----------------
__global__ __launch_bounds__(256) void k_part(const int* __restrict__ src,
                                              const int* __restrict__ dst,
                                              int* __restrict__ gcur,
                                              unsigned int* __restrict__ bucketed) {
    __shared__ int hist[NBKT];
    __shared__ int lcur[NBKT];
    __shared__ unsigned int pbuf[EPB];
    __shared__ unsigned short bbuf[EPB];
    int tid = threadIdx.x;
    for (int i = tid; i < NBKT; i += 256) hist[i] = 0;
    __syncthreads();
    int e0 = blockIdx.x * EPB;
    int cnt = min(EPB, N_EDGES - e0);
    for (int i = tid; i < cnt; i += 256) {
        int s = src[e0 + i], d = dst[e0 + i];
        int b = d >> W_LOG;
        pbuf[i] = ((unsigned int)s << W_LOG) | (unsigned int)(d & (W - 1));
        bbuf[i] = (unsigned short)b;
        atomicAdd(&hist[b], 1);
    }
    __syncthreads();
    for (int b = tid; b < NBKT; b += 256) {
        int h = hist[b];
        lcur[b] = h > 0 ? atomicAdd(&gcur[b], h) : 0;
    }
    __syncthreads();
    for (int i = tid; i < cnt; i += 256) {
        int b = bbuf[i];
        int pos = atomicAdd(&lcur[b], 1);
        if (pos < CAP) bucketed[(size_t)b * CAP + pos] = pbuf[i];
    }
}

// ---------------- per-bucket counting sort by dst-low -> CSR + meta + dinv ----------------
__global__ __launch_bounds__(256) void k_sort(const unsigned int* __restrict__ bucketed,
                                              const int* __restrict__ gcur,
                                              int* __restrict__ sorted,
                                              int2* __restrict__ meta,
                                              float* __restrict__ dinv) {
    __shared__ int hist[W], pre[W], cur[W];
    __shared__ int sbuf[CAP];
    int tid = threadIdx.x, b = blockIdx.x;
    int cnt = min(gcur[b], CAP);
    const unsigned int* bp = bucketed + (size_t)b * CAP;
    if (tid < W) hist[tid] = 0;
    __syncthreads();
    for (int i = tid; i < cnt; i += 256) atomicAdd(&hist[bp[i] & (W - 1)], 1);
    __syncthreads();
    if (tid < W) pre[tid] = hist[tid];
    __syncthreads();
    for (int off = 1; off < W; off <<= 1) {
        int v = (tid < W && tid >= off) ? pre[tid - off] : 0;
        __syncthreads();
        if (tid < W) pre[tid] += v;       // inclusive scan
        __syncthreads();
    }
    if (tid < W) cur[tid] = pre[tid] - hist[tid];   // exclusive base
    __syncthreads();
    for (int i = tid; i < cnt; i += 256) {
        unsigned int p = bp[i];
        int pos = atomicAdd(&cur[p & (W - 1)], 1);
        sbuf[pos] = (int)(p >> W_LOG);
    }
    __syncthreads();
    int* so = sorted + (size_t)b * CAP;
    for (int i = tid; i < cnt; i += 256) so[i] = sbuf[i];
    int node = b * W + tid;
    if (tid < W && node < N_NODES) {
        int h = hist[tid];
        meta[node] = make_int2(b * CAP + (pre[tid] - h), h);
        dinv[node] = h > 0 ? rsqrtf((float)h) : 0.f;
    }
}

// ---------------- layer-1 GEMM via bf16 MFMA, direct-to-register A ----------------
// C[100000 x 64] = x @ W; cols 0..31 -> h1c (bf16, *dinv[row]), 32..63 -> r1 (f32).
__global__ __launch_bounds__(512) void k_gemm1(
    const float* __restrict__ x, const float* __restrict__ wi,
    const float* __restrict__ wr, const float* __restrict__ dinv,
    unsigned short* __restrict__ h1c, float* __restrict__ r1) {
    __shared__ unsigned short wt[64 * 256];     // 32KB  W^T: [col][k] bf16, slot-swizzled
    int tid = threadIdx.x;

    for (int i = tid; i < 8192; i += 512) {
        int ksk = i >> 12, f = (i >> 4) & 255, o = i & 15;
        int col = ksk * 16 + o;
        int slot = (f >> 3) ^ (col & 7);
        wt[col * 256 + slot * 8 + (f & 7)] = f2bf(wi[i]);
    }
    for (int i = tid; i < 8192; i += 512) {
        int ksk = i >> 12, f = (i >> 4) & 255, o = i & 15;
        int col = 32 + ksk * 16 + o;
        int slot = (f >> 3) ^ (col & 7);
        wt[col * 256 + slot * 8 + (f & 7)] = f2bf(wr[i]);
    }
    __syncthreads();

    int lane = tid & 63;
    int wv   = tid >> 6;                        // wave 0..7
    int base = blockIdx.x * 128 + wv * 16;      // 16 rows per wave
    int row16 = lane & 15;
    int akg   = lane >> 4;                      // A k-group 0..3
    int gr = min(base + row16, N_NODES - 1);
    const float* xp = x + (size_t)gr * F_IN + akg * 8;

    f32x4 acc[4] = {{0, 0, 0, 0}, {0, 0, 0, 0}, {0, 0, 0, 0}, {0, 0, 0, 0}};

    #pragma unroll
    for (int ks = 0; ks < 8; ++ks) {
        float4 v0 = *reinterpret_cast<const float4*>(xp + ks * 32);
        float4 v1 = *reinterpret_cast<const float4*>(xp + ks * 32 + 4);
        u16x8 p;
        p[0] = f2bf(v0.x); p[1] = f2bf(v0.y); p[2] = f2bf(v0.z); p[3] = f2bf(v0.w);
        p[4] = f2bf(v1.x); p[5] = f2bf(v1.y); p[6] = f2bf(v1.z); p[7] = f2bf(v1.w);
        bf16x8 af = __builtin_bit_cast(bf16x8, p);
        #pragma unroll
        for (int c = 0; c < 4; ++c) {
            int col = c * 16 + row16;
            int slot = (ks * 4 + akg) ^ (col & 7);
            bf16x8 bfr = *reinterpret_cast<const bf16x8*>(&wt[col * 256 + slot * 8]);
            acc[c] = __builtin_amdgcn_mfma_f32_16x16x32_bf16(af, bfr, acc[c], 0, 0, 0);
        }
    }

    // D layout: col = lane&15, row = (lane>>4)*4 + reg
    float dv[4];
    #pragma unroll
    for (int r = 0; r < 4; ++r) {
        int n = base + (lane >> 4) * 4 + r;
        dv[r] = (n < N_NODES) ? dinv[n] : 0.f;
    }
    #pragma unroll
    for (int c = 0; c < 4; ++c) {
        #pragma unroll
        for (int r = 0; r < 4; ++r) {
            int n = base + (lane >> 4) * 4 + r;
            if (n < N_NODES) {
                int col = c * 16 + row16;
                float v = acc[c][r];
                if (col < KH) h1c[(size_t)n * KH + col] = f2bf(v * dv[r]);
                else          r1[(size_t)n * KH + (col - KH)] = v;
            }
        }
    }
}

// ---------------- layer-1 gather (32 cols, one 64B row/edge) + fused post1 ----------------
// 8 lanes/node (q=0..7, 4 cols each). After edge loop: bias+relu, stack-exchange via
// shfl_xor(4), h assembly via 4 in-wave shuffles, collapsed layer-2 projections
// (q<4 -> h2 table bf16 *dinv; q>=4 -> root r2m).
__global__ __launch_bounds__(512) void k_gath1p(
    const int* __restrict__ sorted, const int2* __restrict__ meta,
    const float* __restrict__ dinv, const unsigned short* __restrict__ h1c,
    const float* __restrict__ r1, const float* __restrict__ b1,
    const float* __restrict__ wi2, const float* __restrict__ wr2,
    float* __restrict__ hout, unsigned short* __restrict__ h2t,
    float* __restrict__ r2m) {
    __shared__ float wm[512];   // [0:256) mean init_w2, [256:512) mean root_w2
    int tid = threadIdx.x;
    if (tid < 256)      wm[tid] = 0.5f * (wi2[tid] + wi2[256 + tid]);
    else                wm[tid] = 0.5f * (wr2[tid - 256] + wr2[256 + tid - 256]);
    __syncthreads();

    int t = blockIdx.x * 512 + tid;
    int n = t >> 3, q = t & 7;
    if (n >= N_NODES) return;
    int2 m = meta[n];
    const int* sp = sorted + m.x;
    float ax = 0, ay = 0, az = 0, aw = 0;
    int j = 0;
    for (; j + 4 <= m.y; j += 4) {
        int s0 = sp[j], s1 = sp[j + 1], s2 = sp[j + 2], s3 = sp[j + 3];
        ushort4 v0 = *reinterpret_cast<const ushort4*>(h1c + (size_t)s0 * KH + q * 4);
        ushort4 v1 = *reinterpret_cast<const ushort4*>(h1c + (size_t)s1 * KH + q * 4);
        ushort4 v2 = *reinterpret_cast<const ushort4*>(h1c + (size_t)s2 * KH + q * 4);
        ushort4 v3 = *reinterpret_cast<const ushort4*>(h1c + (size_t)s3 * KH + q * 4);
        ax += (bf2f(v0.x) + bf2f(v1.x)) + (bf2f(v2.x) + bf2f(v3.x));
        ay += (bf2f(v0.y) + bf2f(v1.y)) + (bf2f(v2.y) + bf2f(v3.y));
        az += (bf2f(v0.z) + bf2f(v1.z)) + (bf2f(v2.z) + bf2f(v3.z));
        aw += (bf2f(v0.w) + bf2f(v1.w)) + (bf2f(v2.w) + bf2f(v3.w));
    }
    for (; j < m.y; ++j) {
        int s0 = sp[j];
        ushort4 v0 = *reinterpret_cast<const ushort4*>(h1c + (size_t)s0 * KH + q * 4);
        ax += bf2f(v0.x); ay += bf2f(v0.y); az += bf2f(v0.z); aw += bf2f(v0.w);
    }
    float dn = dinv[n];
    float4 rv = *reinterpret_cast<const float4*>(r1 + (size_t)n * KH + q * 4);
    float zi[4];
    zi[0] = fmaxf(ax * dn + rv.x + b1[q * 4 + 0], 0.f);
    zi[1] = fmaxf(ay * dn + rv.y + b1[q * 4 + 1], 0.f);
    zi[2] = fmaxf(az * dn + rv.z + b1[q * 4 + 2], 0.f);
    zi[3] = fmaxf(aw * dn + rv.w + b1[q * 4 + 3], 0.f);
    // exchange stacks (lane q <-> q^4 within the 8-lane node group)
    float h4[4];
    #pragma unroll
    for (int i = 0; i < 4; ++i)
        h4[i] = 0.5f * (zi[i] + __shfl_xor(zi[i], 4));
    if (q < 4)
        *reinterpret_cast<float4*>(hout + (size_t)n * HID + q * 4) =
            make_float4(h4[0], h4[1], h4[2], h4[3]);
    // assemble full h[16] via in-wave shuffles from lanes q=0..3 of this group
    int lane = tid & 63;
    int bl = lane & 56;                 // group base lane
    float hf[16];
    #pragma unroll
    for (int jj = 0; jj < 4; ++jj)
        #pragma unroll
        for (int i = 0; i < 4; ++i)
            hf[jj * 4 + i] = __shfl(h4[i], bl + jj);
    // collapsed layer-2 projection: q<4 computes init (h2t), q>=4 computes root (r2m)
    const float* wsel = (q < 4) ? wm : wm + 256;
    int ocb = (q & 3) * 4;
    float o4[4] = {0, 0, 0, 0};
    #pragma unroll
    for (int k = 0; k < HID; ++k) {
        float hv = hf[k];
        o4[0] += hv * wsel[k * 16 + ocb + 0];
        o4[1] += hv * wsel[k * 16 + ocb + 1];
        o4[2] += hv * wsel[k * 16 + ocb + 2];
        o4[3] += hv * wsel[k * 16 + ocb + 3];
    }
    if (q < 4) {
        ushort4 hw;
        hw.x = f2bf(o4[0] * dn); hw.y = f2bf(o4[1] * dn);
        hw.z = f2bf(o4[2] * dn); hw.w = f2bf(o4[3] * dn);
        *reinterpret_cast<ushort4*>(h2t + (size_t)n * HID + ocb) = hw;
    } else {
        *reinterpret_cast<float4*>(r2m + (size_t)n * HID + ocb) =
            make_float4(o4[0], o4[1], o4[2], o4[3]);
    }
}

// ---------------- layer-2 gather (16 cols) + fused post2 (log_softmax) ----------------
// 4 lanes/node; in-wave xor-reduce for max and sum-exp.
__global__ __launch_bounds__(256) void k_gath2p(
    const int* __restrict__ sorted, const int2* __restrict__ meta,
    const float* __restrict__ dinv, const unsigned short* __restrict__ h2t,
    const float* __restrict__ r2m, const float* __restrict__ b2,
    float* __restrict__ out) {
    int t = blockIdx.x * 256 + threadIdx.x;
    int n = t >> 2, q = t & 3;
    if (n >= N_NODES) return;
    int2 m = meta[n];
    const int* sp = sorted + m.x;
    float ax = 0, ay = 0, az = 0, aw = 0;
    int j = 0;
    for (; j + 4 <= m.y; j += 4) {
        int s0 = sp[j], s1 = sp[j + 1], s2 = sp[j + 2], s3 = sp[j + 3];
        ushort4 v0 = *reinterpret_cast<const ushort4*>(h2t + (size_t)s0 * HID + q * 4);
        ushort4 v1 = *reinterpret_cast<const ushort4*>(h2t + (size_t)s1 * HID + q * 4);
        ushort4 v2 = *reinterpret_cast<const ushort4*>(h2t + (size_t)s2 * HID + q * 4);
        ushort4 v3 = *reinterpret_cast<const ushort4*>(h2t + (size_t)s3 * HID + q * 4);
        ax += (bf2f(v0.x) + bf2f(v1.x)) + (bf2f(v2.x) + bf2f(v3.x));
        ay += (bf2f(v0.y) + bf2f(v1.y)) + (bf2f(v2.y) + bf2f(v3.y));
        az += (bf2f(v0.z) + bf2f(v1.z)) + (bf2f(v2.z) + bf2f(v3.z));
        aw += (bf2f(v0.w) + bf2f(v1.w)) + (bf2f(v2.w) + bf2f(v3.w));
    }
    for (; j < m.y; ++j) {
        int s0 = sp[j];
        ushort4 v0 = *reinterpret_cast<const ushort4*>(h2t + (size_t)s0 * HID + q * 4);
        ax += bf2f(v0.x); ay += bf2f(v0.y); az += bf2f(v0.z); aw += bf2f(v0.w);
    }
    float dn = dinv[n];
    float4 rv = *reinterpret_cast<const float4*>(r2m + (size_t)n * HID + q * 4);
    float z[4];
    z[0] = ax * dn + rv.x + 0.5f * (b2[q * 4 + 0] + b2[16 + q * 4 + 0]);
    z[1] = ay * dn + rv.y + 0.5f * (b2[q * 4 + 1] + b2[16 + q * 4 + 1]);
    z[2] = az * dn + rv.z + 0.5f * (b2[q * 4 + 2] + b2[16 + q * 4 + 2]);
    z[3] = aw * dn + rv.w + 0.5f * (b2[q * 4 + 3] + b2[16 + q * 4 + 3]);
    float lm = fmaxf(fmaxf(z[0], z[1]), fmaxf(z[2], z[3]));
    lm = fmaxf(lm, __shfl_xor(lm, 1));
    float mx = fmaxf(lm, __shfl_xor(lm, 2));
    float sl = expf(z[0] - mx) + expf(z[1] - mx) + expf(z[2] - mx) + expf(z[3] - mx);
    sl += __shfl_xor(sl, 1);
    float s = sl + __shfl_xor(sl, 2);
    float ls = logf(s);
    *reinterpret_cast<float4*>(out + (size_t)n * C_OUT + q * 4) =
        make_float4(z[0] - mx - ls, z[1] - mx - ls, z[2] - mx - ls, z[3] - mx - ls);
}

extern "C" void kernel_launch(void* const* d_in, const int* in_sizes, int n_in,
                              void* d_out, int out_size, void* d_ws, size_t ws_size,
                              hipStream_t stream) {
    const float* x   = (const float*)d_in[0];
    const int*   ei  = (const int*)d_in[1];     // [2, E] int32
    const float* wi1 = (const float*)d_in[2];
    const float* wr1 = (const float*)d_in[3];
    const float* b1  = (const float*)d_in[4];
    const float* wi2 = (const float*)d_in[5];
    const float* wr2 = (const float*)d_in[6];
    const float* b2  = (const float*)d_in[7];
    float* out = (float*)d_out;                  // [N*16 log_softmax][N*16 h]

    // ---- workspace layout (all offsets 64B-aligned) ----
    int* gcur = (int*)d_ws;                                      // 1024
    unsigned int* bucketed = (unsigned int*)(gcur + 1024);       // NBKT*CAP
    int* sorted = (int*)(bucketed + (size_t)NBKT * CAP);         // NBKT*CAP
    int2* meta  = (int2*)(sorted + (size_t)NBKT * CAP);          // N
    float* dinv = (float*)(meta + N_NODES);                      // N
    float* r1   = dinv + N_NODES;                                // 32N
    float* r2m  = r1 + (size_t)N_NODES * KH;                     // 16N
    unsigned short* h1c = (unsigned short*)(r2m + (size_t)N_NODES * HID); // 32N u16
    unsigned short* h2t = h1c + (size_t)N_NODES * KH;                     // 16N u16

    const int* srcI = ei;
    const int* dstI = ei + N_EDGES;

    hipMemsetAsync(gcur, 0, 1024 * sizeof(int), stream);

    k_part<<<(N_EDGES + EPB - 1) / EPB, 256, 0, stream>>>(srcI, dstI, gcur, bucketed);
    k_sort<<<NBKT, 256, 0, stream>>>(bucketed, gcur, sorted, meta, dinv);
    k_gemm1<<<(N_NODES + 127) / 128, 512, 0, stream>>>(x, wi1, wr1, dinv, h1c, r1);
    k_gath1p<<<(N_NODES * 8 + 511) / 512, 512, 0, stream>>>(
        sorted, meta, dinv, h1c, r1, b1, wi2, wr2,
        out + (size_t)N_NODES * C_OUT, h2t, r2m);
    k_gath2p<<<(N_NODES * 4 + 255) / 256, 256, 0, stream>>>(
        sorted, meta, dinv, h2t, r2m, b2, out);
}

// Round 8
// 312.471 us; speedup vs baseline: 5.1029x; 1.0617x over previous
//
#include <hip/hip_runtime.h>
#include <cstdint>
#include <cstddef>

#define N_NODES 100000
#define N_EDGES 3200000
#define F_IN    256
#define HID     16
#define KH      32      // K stacks (2) * HID (16)
#define C_OUT   16

#define W_LOG   7
#define W       128                     // dst-window (nodes per bucket)
#define NBKT    782                     // ceil(N_NODES / W)
#define CAP     4608                    // bucket capacity (mean 4092, +8 sigma)
#define EPB     4096                    // edges per partition block
#define PART_BLOCKS 782                 // ceil(E / EPB)
#define GEMM_BLOCKS 782                 // ceil(N / 128)

typedef short  bf16x8 __attribute__((ext_vector_type(8)));
typedef float  f32x4  __attribute__((ext_vector_type(4)));
typedef unsigned short u16x8 __attribute__((ext_vector_type(8)));

__device__ __forceinline__ unsigned short f2bf(float f) {
    uint32_t u = __builtin_bit_cast(uint32_t, f);
    u += 0x7fffu + ((u >> 16) & 1u);      // round-to-nearest-even
    return (unsigned short)(u >> 16);
}
__device__ __forceinline__ float bf2f(unsigned short s) {
    return __builtin_bit_cast(float, (uint32_t)s << 16);
}

struct PartSmem {
    int hist[NBKT];
    int lcur[NBKT];
    unsigned int pbuf[EPB];
    unsigned short bbuf[EPB];
};
struct GemmSmem {
    unsigned short wt[64 * 256];        // 32KB W^T: [col][k] bf16, slot-swizzled
};
union FusedSmem { PartSmem p; GemmSmem g; };

// ---------------- fused: edge partition (blocks 0..781) || layer-1 MFMA GEMM ----------------
__global__ __launch_bounds__(512) void k_partgemm(
    const int* __restrict__ src, const int* __restrict__ dst,
    int* __restrict__ gcur, unsigned int* __restrict__ bucketed,
    const float* __restrict__ x, const float* __restrict__ wi,
    const float* __restrict__ wr, const float* __restrict__ dinv_unused,
    unsigned short* __restrict__ h1c, unsigned short* __restrict__ r1b) {
    __shared__ FusedSmem sm;
    int tid = threadIdx.x;

    if (blockIdx.x < PART_BLOCKS) {
        // ======== partition branch ========
        int pb = blockIdx.x;
        for (int i = tid; i < NBKT; i += 512) sm.p.hist[i] = 0;
        __syncthreads();
        int e0 = pb * EPB;
        int cnt = min(EPB, N_EDGES - e0);
        for (int i = tid; i < cnt; i += 512) {
            int s = src[e0 + i], d = dst[e0 + i];
            int b = d >> W_LOG;
            sm.p.pbuf[i] = ((unsigned int)s << W_LOG) | (unsigned int)(d & (W - 1));
            sm.p.bbuf[i] = (unsigned short)b;
            atomicAdd(&sm.p.hist[b], 1);
        }
        __syncthreads();
        for (int b = tid; b < NBKT; b += 512) {
            int h = sm.p.hist[b];
            sm.p.lcur[b] = h > 0 ? atomicAdd(&gcur[b], h) : 0;
        }
        __syncthreads();
        for (int i = tid; i < cnt; i += 512) {
            int b = sm.p.bbuf[i];
            int pos = atomicAdd(&sm.p.lcur[b], 1);
            if (pos < CAP) bucketed[(size_t)b * CAP + pos] = sm.p.pbuf[i];
        }
        return;
    }

    // ======== gemm branch ========
    int gb = blockIdx.x - PART_BLOCKS;
    for (int i = tid; i < 8192; i += 512) {
        int ksk = i >> 12, f = (i >> 4) & 255, o = i & 15;
        int col = ksk * 16 + o;
        int slot = (f >> 3) ^ (col & 7);
        sm.g.wt[col * 256 + slot * 8 + (f & 7)] = f2bf(wi[i]);
    }
    for (int i = tid; i < 8192; i += 512) {
        int ksk = i >> 12, f = (i >> 4) & 255, o = i & 15;
        int col = 32 + ksk * 16 + o;
        int slot = (f >> 3) ^ (col & 7);
        sm.g.wt[col * 256 + slot * 8 + (f & 7)] = f2bf(wr[i]);
    }
    __syncthreads();

    int lane = tid & 63;
    int wv   = tid >> 6;                        // wave 0..7
    int base = gb * 128 + wv * 16;              // 16 rows per wave
    int row16 = lane & 15;
    int akg   = lane >> 4;                      // A k-group 0..3
    int gr = min(base + row16, N_NODES - 1);
    const float* xp = x + (size_t)gr * F_IN + akg * 8;

    f32x4 acc[4] = {{0, 0, 0, 0}, {0, 0, 0, 0}, {0, 0, 0, 0}, {0, 0, 0, 0}};

    #pragma unroll
    for (int ks = 0; ks < 8; ++ks) {
        float4 v0 = *reinterpret_cast<const float4*>(xp + ks * 32);
        float4 v1 = *reinterpret_cast<const float4*>(xp + ks * 32 + 4);
        u16x8 p;
        p[0] = f2bf(v0.x); p[1] = f2bf(v0.y); p[2] = f2bf(v0.z); p[3] = f2bf(v0.w);
        p[4] = f2bf(v1.x); p[5] = f2bf(v1.y); p[6] = f2bf(v1.z); p[7] = f2bf(v1.w);
        bf16x8 af = __builtin_bit_cast(bf16x8, p);
        #pragma unroll
        for (int c = 0; c < 4; ++c) {
            int col = c * 16 + row16;
            int slot = (ks * 4 + akg) ^ (col & 7);
            bf16x8 bfr = *reinterpret_cast<const bf16x8*>(&sm.g.wt[col * 256 + slot * 8]);
            acc[c] = __builtin_amdgcn_mfma_f32_16x16x32_bf16(af, bfr, acc[c], 0, 0, 0);
        }
    }

    // D layout: col = lane&15, row = (lane>>4)*4 + reg. NOTE: dinv not ready yet
    // (partition runs concurrently) -> h1c written UNSCALED; gath1p scales by
    // dinv[src] via a per-edge multiply... instead we fold dinv[src] later:
    // store unscaled; gath1p loads dinv per edge? That costs per-edge loads.
    // Cheaper: k_sort (which runs after) rescales h1c rows. See k_scale below.
    #pragma unroll
    for (int c = 0; c < 4; ++c) {
        #pragma unroll
        for (int r = 0; r < 4; ++r) {
            int n = base + (lane >> 4) * 4 + r;
            if (n < N_NODES) {
                int col = c * 16 + row16;
                float v = acc[c][r];
                if (col < KH) h1c[(size_t)n * KH + col] = f2bf(v);
                else          r1b[(size_t)n * KH + (col - KH)] = f2bf(v);
            }
        }
    }
}

// ---------------- per-bucket counting sort -> CSR + meta + dinv, then rescale h1c ----
__global__ __launch_bounds__(256) void k_sort(const unsigned int* __restrict__ bucketed,
                                              const int* __restrict__ gcur,
                                              int* __restrict__ sorted,
                                              int2* __restrict__ meta,
                                              float* __restrict__ dinv,
                                              unsigned short* __restrict__ h1c) {
    __shared__ int hist[W], pre[W], cur[W];
    __shared__ int sbuf[CAP];
    int tid = threadIdx.x, b = blockIdx.x;
    int cnt = min(gcur[b], CAP);
    const unsigned int* bp = bucketed + (size_t)b * CAP;
    if (tid < W) hist[tid] = 0;
    __syncthreads();
    for (int i = tid; i < cnt; i += 256) atomicAdd(&hist[bp[i] & (W - 1)], 1);
    __syncthreads();
    if (tid < W) pre[tid] = hist[tid];
    __syncthreads();
    for (int off = 1; off < W; off <<= 1) {
        int v = (tid < W && tid >= off) ? pre[tid - off] : 0;
        __syncthreads();
        if (tid < W) pre[tid] += v;       // inclusive scan
        __syncthreads();
    }
    if (tid < W) cur[tid] = pre[tid] - hist[tid];   // exclusive base
    __syncthreads();
    for (int i = tid; i < cnt; i += 256) {
        unsigned int p = bp[i];
        int pos = atomicAdd(&cur[p & (W - 1)], 1);
        sbuf[pos] = (int)(p >> W_LOG);
    }
    __syncthreads();
    int* so = sorted + (size_t)b * CAP;
    for (int i = tid; i < cnt; i += 256) so[i] = sbuf[i];
    int node = b * W + tid;
    float dv = 0.f;
    if (tid < W && node < N_NODES) {
        int h = hist[tid];
        meta[node] = make_int2(b * CAP + (pre[tid] - h), h);
        dv = h > 0 ? rsqrtf((float)h) : 0.f;
        dinv[node] = dv;
    }
    __syncthreads();
    // rescale this window's h1c rows by dinv (gemm wrote them unscaled):
    // 2 threads per node, 16 cols each (128 nodes * 2 = 256 threads).
    int rn = b * W + (tid >> 1);
    if (rn < N_NODES) {
        float d2 = (tid & 1) ? hist[0] : 0.f;  // placeholder to keep reg pressure low
        (void)d2;
        float dr = dinv[rn];
        u16x8* row = reinterpret_cast<u16x8*>(h1c + (size_t)rn * KH + (tid & 1) * 16);
        #pragma unroll
        for (int g = 0; g < 2; ++g) {
            u16x8 v = row[g];
            #pragma unroll
            for (int i = 0; i < 8; ++i) v[i] = f2bf(bf2f(v[i]) * dr);
            row[g] = v;
        }
    }
}

// ---------------- layer-1 gather (32 cols, 4 lanes/node x 16B) + fused post1 ----------------
__global__ __launch_bounds__(512) void k_gath1p(
    const int* __restrict__ sorted, const int2* __restrict__ meta,
    const float* __restrict__ dinv, const unsigned short* __restrict__ h1c,
    const unsigned short* __restrict__ r1b, const float* __restrict__ b1,
    const float* __restrict__ wi2, const float* __restrict__ wr2,
    float* __restrict__ hout, unsigned short* __restrict__ h2t,
    unsigned short* __restrict__ r2mb) {
    __shared__ float wm[512];   // [0:256) mean init_w2, [256:512) mean root_w2
    __shared__ float sb1[32];
    int tid = threadIdx.x;
    if (tid < 256)      wm[tid] = 0.5f * (wi2[tid] + wi2[256 + tid]);
    else                wm[tid] = 0.5f * (wr2[tid - 256] + wr2[tid]);
    if (tid < 32) sb1[tid] = b1[tid];
    __syncthreads();

    int t = blockIdx.x * 512 + tid;
    int n = t >> 2, q = t & 3;
    if (n >= N_NODES) return;
    int2 m = meta[n];
    const int* sp = sorted + m.x;
    float a[8] = {0, 0, 0, 0, 0, 0, 0, 0};
    int j = 0;
    for (; j + 4 <= m.y; j += 4) {
        int s0 = sp[j], s1 = sp[j + 1], s2 = sp[j + 2], s3 = sp[j + 3];
        u16x8 v0 = *reinterpret_cast<const u16x8*>(h1c + (size_t)s0 * KH + q * 8);
        u16x8 v1 = *reinterpret_cast<const u16x8*>(h1c + (size_t)s1 * KH + q * 8);
        u16x8 v2 = *reinterpret_cast<const u16x8*>(h1c + (size_t)s2 * KH + q * 8);
        u16x8 v3 = *reinterpret_cast<const u16x8*>(h1c + (size_t)s3 * KH + q * 8);
        #pragma unroll
        for (int i = 0; i < 8; ++i)
            a[i] += (bf2f(v0[i]) + bf2f(v1[i])) + (bf2f(v2[i]) + bf2f(v3[i]));
    }
    for (; j < m.y; ++j) {
        int s0 = sp[j];
        u16x8 v0 = *reinterpret_cast<const u16x8*>(h1c + (size_t)s0 * KH + q * 8);
        #pragma unroll
        for (int i = 0; i < 8; ++i) a[i] += bf2f(v0[i]);
    }
    float dn = dinv[n];
    u16x8 rt = *reinterpret_cast<const u16x8*>(r1b + (size_t)n * KH + q * 8);
    float h8[8];
    #pragma unroll
    for (int i = 0; i < 8; ++i) {
        float zi = fmaxf(a[i] * dn + bf2f(rt[i]) + sb1[q * 8 + i], 0.f);
        h8[i] = zi;
    }
    // stack exchange: lane q ^ 2 holds the other stack's matching cols
    #pragma unroll
    for (int i = 0; i < 8; ++i)
        h8[i] = 0.5f * (h8[i] + __shfl_xor(h8[i], 2));
    if (q < 2) {
        float4* ho = reinterpret_cast<float4*>(hout + (size_t)n * HID + q * 8);
        ho[0] = make_float4(h8[0], h8[1], h8[2], h8[3]);
        ho[1] = make_float4(h8[4], h8[5], h8[6], h8[7]);
    }
    // assemble full h[16] from lanes bl+0 (cols 0-7) and bl+1 (cols 8-15)
    int lane = tid & 63;
    int bl = lane & 60;
    float hf[16];
    #pragma unroll
    for (int kk = 0; kk < 8; ++kk) {
        hf[kk]     = __shfl(h8[kk], bl);
        hf[8 + kk] = __shfl(h8[kk], bl + 1);
    }
    // collapsed layer-2 projection: q<2 -> h2t (init, *dn), q>=2 -> r2mb (root)
    const float* wsel = (q < 2) ? wm : wm + 256;
    int ocb = (q & 1) * 8;
    float o8[8] = {0, 0, 0, 0, 0, 0, 0, 0};
    #pragma unroll
    for (int k = 0; k < HID; ++k) {
        float hv = hf[k];
        #pragma unroll
        for (int i = 0; i < 8; ++i) o8[i] += hv * wsel[k * 16 + ocb + i];
    }
    u16x8 wv8;
    if (q < 2) {
        #pragma unroll
        for (int i = 0; i < 8; ++i) wv8[i] = f2bf(o8[i] * dn);
        *reinterpret_cast<u16x8*>(h2t + (size_t)n * HID + ocb) = wv8;
    } else {
        #pragma unroll
        for (int i = 0; i < 8; ++i) wv8[i] = f2bf(o8[i]);
        *reinterpret_cast<u16x8*>(r2mb + (size_t)n * HID + ocb) = wv8;
    }
}

// ---------------- layer-2 gather (16 cols, 2 lanes/node x 16B) + fused log_softmax ----
__global__ __launch_bounds__(256) void k_gath2p(
    const int* __restrict__ sorted, const int2* __restrict__ meta,
    const float* __restrict__ dinv, const unsigned short* __restrict__ h2t,
    const unsigned short* __restrict__ r2mb, const float* __restrict__ b2,
    float* __restrict__ out) {
    int t = blockIdx.x * 256 + threadIdx.x;
    int n = t >> 1, q = t & 1;
    if (n >= N_NODES) return;
    int2 m = meta[n];
    const int* sp = sorted + m.x;
    float a[8] = {0, 0, 0, 0, 0, 0, 0, 0};
    int j = 0;
    for (; j + 4 <= m.y; j += 4) {
        int s0 = sp[j], s1 = sp[j + 1], s2 = sp[j + 2], s3 = sp[j + 3];
        u16x8 v0 = *reinterpret_cast<const u16x8*>(h2t + (size_t)s0 * HID + q * 8);
        u16x8 v1 = *reinterpret_cast<const u16x8*>(h2t + (size_t)s1 * HID + q * 8);
        u16x8 v2 = *reinterpret_cast<const u16x8*>(h2t + (size_t)s2 * HID + q * 8);
        u16x8 v3 = *reinterpret_cast<const u16x8*>(h2t + (size_t)s3 * HID + q * 8);
        #pragma unroll
        for (int i = 0; i < 8; ++i)
            a[i] += (bf2f(v0[i]) + bf2f(v1[i])) + (bf2f(v2[i]) + bf2f(v3[i]));
    }
    for (; j < m.y; ++j) {
        int s0 = sp[j];
        u16x8 v0 = *reinterpret_cast<const u16x8*>(h2t + (size_t)s0 * HID + q * 8);
        #pragma unroll
        for (int i = 0; i < 8; ++i) a[i] += bf2f(v0[i]);
    }
    float dn = dinv[n];
    u16x8 rt = *reinterpret_cast<const u16x8*>(r2mb + (size_t)n * HID + q * 8);
    float z[8];
    float lm = -1e30f;
    #pragma unroll
    for (int i = 0; i < 8; ++i) {
        int c = q * 8 + i;
        z[i] = a[i] * dn + bf2f(rt[i]) + 0.5f * (b2[c] + b2[16 + c]);
        lm = fmaxf(lm, z[i]);
    }
    float mx = fmaxf(lm, __shfl_xor(lm, 1));
    float sl = 0.f;
    #pragma unroll
    for (int i = 0; i < 8; ++i) sl += expf(z[i] - mx);
    float s = sl + __shfl_xor(sl, 1);
    float ls = logf(s);
    float4* o4 = reinterpret_cast<float4*>(out + (size_t)n * C_OUT + q * 8);
    o4[0] = make_float4(z[0] - mx - ls, z[1] - mx - ls, z[2] - mx - ls, z[3] - mx - ls);
    o4[1] = make_float4(z[4] - mx - ls, z[5] - mx - ls, z[6] - mx - ls, z[7] - mx - ls);
}

extern "C" void kernel_launch(void* const* d_in, const int* in_sizes, int n_in,
                              void* d_out, int out_size, void* d_ws, size_t ws_size,
                              hipStream_t stream) {
    const float* x   = (const float*)d_in[0];
    const int*   ei  = (const int*)d_in[1];     // [2, E] int32
    const float* wi1 = (const float*)d_in[2];
    const float* wr1 = (const float*)d_in[3];
    const float* b1  = (const float*)d_in[4];
    const float* wi2 = (const float*)d_in[5];
    const float* wr2 = (const float*)d_in[6];
    const float* b2  = (const float*)d_in[7];
    float* out = (float*)d_out;                  // [N*16 log_softmax][N*16 h]

    // ---- workspace layout (16B-aligned segments) ----
    int* gcur = (int*)d_ws;                                      // 1024
    unsigned int* bucketed = (unsigned int*)(gcur + 1024);       // NBKT*CAP
    int* sorted = (int*)(bucketed + (size_t)NBKT * CAP);         // NBKT*CAP
    int2* meta  = (int2*)(sorted + (size_t)NBKT * CAP);          // N
    float* dinv = (float*)(meta + N_NODES);                      // N
    unsigned short* h1c  = (unsigned short*)(dinv + N_NODES);    // 32N u16
    unsigned short* h2t  = h1c + (size_t)N_NODES * KH;           // 16N u16
    unsigned short* r1b  = h2t + (size_t)N_NODES * HID;          // 32N u16
    unsigned short* r2mb = r1b + (size_t)N_NODES * KH;           // 16N u16

    const int* srcI = ei;
    const int* dstI = ei + N_EDGES;

    hipMemsetAsync(gcur, 0, 1024 * sizeof(int), stream);

    k_partgemm<<<PART_BLOCKS + GEMM_BLOCKS, 512, 0, stream>>>(
        srcI, dstI, gcur, bucketed, x, wi1, wr1, nullptr, h1c, r1b);
    k_sort<<<NBKT, 256, 0, stream>>>(bucketed, gcur, sorted, meta, dinv, h1c);
    k_gath1p<<<(N_NODES * 4 + 511) / 512, 512, 0, stream>>>(
        sorted, meta, dinv, h1c, r1b, b1, wi2, wr2,
        out + (size_t)N_NODES * C_OUT, h2t, r2mb);
    k_gath2p<<<(N_NODES * 2 + 255) / 256, 256, 0, stream>>>(
        sorted, meta, dinv, h2t, r2mb, b2, out);
}